// Round 3
// baseline (177.515 us; speedup 1.0000x reference)
//
#include <hip/hip_runtime.h>
#include <hip/hip_bf16.h>
#include <math.h>

// out[i,f] = tanh(b[f] + a[f] * dot(W[f,:], x[i,:]))
// GEMM M=32768 N=512 K=512, A=x row-major [M,K], B=W row-major [N,K] (B^T layout).
// fp32 emulated via 3-term bf16 split: z = xh*Wh + xh*Wl + xl*Wh (exact residual split).

typedef short     bf16x8 __attribute__((ext_vector_type(8)));
typedef float     f32x4  __attribute__((ext_vector_type(4)));
typedef unsigned short u16x4 __attribute__((ext_vector_type(4)));

static constexpr int Mdim = 32768;
static constexpr int Kdim = 512;
static constexpr int Ndim = 512;

// Split one float4 into hi/lo bf16 quads and store to swizzled LDS.
// hi = truncate-to-bf16(v) (top 16 bits); lo = truncate-to-bf16(v - hi) (exact residual).
// Swizzle: 16B slots within a 128B row XOR'd with (row&7) -> conflict-free ds_read_b128.
__device__ __forceinline__ void split_store(unsigned short* __restrict__ hiP,
                                            unsigned short* __restrict__ loP,
                                            int row, int col4, f32x4 v) {
  u16x4 hi, lo;
#pragma unroll
  for (int j = 0; j < 4; ++j) {
    unsigned bbits = __float_as_uint(v[j]);
    hi[j] = (unsigned short)(bbits >> 16);
    float hf = __uint_as_float(bbits & 0xFFFF0000u);
    float lf = v[j] - hf;                       // exact
    lo[j] = (unsigned short)(__float_as_uint(lf) >> 16);
  }
  const int k    = col4 * 4;                    // bf16 index within row, 0..60
  const int slot = k >> 3;                      // 16B slot index, 0..7
  const int off  = row * 64 + ((slot ^ (row & 7)) << 3) + (k & 7); // ushort units
  *(u16x4*)(hiP + off) = hi;
  *(u16x4*)(loP + off) = lo;
}

__global__ __launch_bounds__(256, 2) void gemm_split_tanh(
    const float* __restrict__ X, const float* __restrict__ Wm,
    const float* __restrict__ avec, const float* __restrict__ bvec,
    float* __restrict__ out) {
  // LDS planes: 0=Ahi 1=Alo 2=Bhi 3=Blo, each [128 rows][64 bf16] = 16KB; total 64KB.
  __shared__ unsigned short lds[4][128 * 64];

  const int bid = blockIdx.x;
  const int nB  = bid & 3;        // N fastest: 4 consecutive blocks share the A panel
  const int mB  = bid >> 2;
  const int tid  = threadIdx.x;
  const int lane = tid & 63;
  const int wid  = tid >> 6;      // 4 waves, 2x2 -> each wave owns 64x64 of the 128x128 tile
  const int wm = wid >> 1, wn = wid & 1;

  f32x4 acc[4][4];
#pragma unroll
  for (int i = 0; i < 4; ++i)
#pragma unroll
    for (int j = 0; j < 4; ++j) acc[i][j] = {0.f, 0.f, 0.f, 0.f};

  // Staging: 128x64 fp32 per matrix per K-step; 256 threads x 8 float4 each.
  const int srow  = tid >> 4;     // 0..15 (then +16*i)
  const int scol4 = tid & 15;     // float4 index within the 64-wide row
  const float* Xb = X  + (size_t)mB * 128 * Kdim;
  const float* Wb = Wm + (size_t)nB * 128 * Kdim;

  for (int kt = 0; kt < Kdim / 64; ++kt) {
    const int kbase = kt * 64;
#pragma unroll
    for (int i = 0; i < 8; ++i) {
      const int row = srow + i * 16;
      f32x4 va = *(const f32x4*)(Xb + (size_t)row * Kdim + kbase + scol4 * 4);
      f32x4 vb = *(const f32x4*)(Wb + (size_t)row * Kdim + kbase + scol4 * 4);
      split_store(lds[0], lds[1], row, scol4, va);
      split_store(lds[2], lds[3], row, scol4, vb);
    }
    __syncthreads();

#pragma unroll
    for (int ks = 0; ks < 2; ++ks) {
      bf16x8 ah[4], al[4], bh[4], bl[4];
      const int slotBase = ks * 4 + (lane >> 4);   // which 16B slot (8 bf16 along K)
#pragma unroll
      for (int mi = 0; mi < 4; ++mi) {
        const int row = wm * 64 + mi * 16 + (lane & 15);
        const int off = row * 64 + ((slotBase ^ (row & 7)) << 3);
        ah[mi] = *(const bf16x8*)&lds[0][off];
        al[mi] = *(const bf16x8*)&lds[1][off];
      }
#pragma unroll
      for (int ni = 0; ni < 4; ++ni) {
        const int row = wn * 64 + ni * 16 + (lane & 15);
        const int off = row * 64 + ((slotBase ^ (row & 7)) << 3);
        bh[ni] = *(const bf16x8*)&lds[2][off];
        bl[ni] = *(const bf16x8*)&lds[3][off];
      }
#pragma unroll
      for (int mi = 0; mi < 4; ++mi)
#pragma unroll
        for (int ni = 0; ni < 4; ++ni) {
          acc[mi][ni] = __builtin_amdgcn_mfma_f32_16x16x32_bf16(ah[mi], bh[ni], acc[mi][ni], 0, 0, 0);
          acc[mi][ni] = __builtin_amdgcn_mfma_f32_16x16x32_bf16(ah[mi], bl[ni], acc[mi][ni], 0, 0, 0);
          acc[mi][ni] = __builtin_amdgcn_mfma_f32_16x16x32_bf16(al[mi], bh[ni], acc[mi][ni], 0, 0, 0);
        }
    }
    __syncthreads();
  }

  // Epilogue: C/D layout for 16x16x32: col = lane&15, row = (lane>>4)*4 + reg.
  const int c  = lane & 15;
  const int rq = (lane >> 4) * 4;
#pragma unroll
  for (int ni = 0; ni < 4; ++ni) {
    const int gc = nB * 128 + wn * 64 + ni * 16 + c;
    const float aa = avec[gc];
    const float bb = bvec[gc];
#pragma unroll
    for (int mi = 0; mi < 4; ++mi) {
      const int gr = mB * 128 + wm * 64 + mi * 16 + rq;
      f32x4 v = acc[mi][ni];
#pragma unroll
      for (int j = 0; j < 4; ++j) {
        out[(size_t)(gr + j) * Ndim + gc] = tanhf(aa * v[j] + bb);
      }
    }
  }
}

extern "C" void kernel_launch(void* const* d_in, const int* in_sizes, int n_in,
                              void* d_out, int out_size, void* d_ws, size_t ws_size,
                              hipStream_t stream) {
  const float* X  = (const float*)d_in[0];
  const float* Wm = (const float*)d_in[1];
  const float* av = (const float*)d_in[2];
  const float* bv = (const float*)d_in[3];
  float* out = (float*)d_out;
  dim3 grid((Mdim / 128) * (Ndim / 128));  // 1024 blocks, N fastest within the index
  dim3 block(256);
  gemm_split_tanh<<<grid, block, 0, stream>>>(X, Wm, av, bv, out);
}

// Round 4
// 157.925 us; speedup vs baseline: 1.1240x; 1.1240x over previous
//
#include <hip/hip_runtime.h>
#include <hip/hip_bf16.h>
#include <math.h>

// out[i,f] = tanh(b[f] + a[f] * dot(W[f,:], x[i,:]))
// GEMM M=32768 N=512 K=512, A=x row-major [M,K], B=W row-major [N,K] (B^T layout).
// fp32 via 3-term bf16 split (RNE + exact residual): z = xh*Wh + xh*Wl + xl*Wh.
// 512 threads = 8 waves (2x4), 128x128 tile, BK=64, single-buffered LDS with
// the measured-zero-conflict XOR swizzle; prefetch next K-tile under MFMA.

typedef short        bf16x8 __attribute__((ext_vector_type(8)));
typedef float        f32x4  __attribute__((ext_vector_type(4)));
typedef unsigned int u32x2  __attribute__((ext_vector_type(2)));

static constexpr int Mdim = 32768;
static constexpr int Kdim = 512;
static constexpr int Ndim = 512;

__device__ __forceinline__ unsigned cvt_pk_bf16(float a, float b) {
  unsigned r;  // r.lo16 = bf16_rne(a), r.hi16 = bf16_rne(b)
  asm("v_cvt_pk_bf16_f32 %0, %1, %2" : "=v"(r) : "v"(a), "v"(b));
  return r;
}

// Split 4 fp32 into packed-bf16 hi (RNE) and exact-residual lo (RNE of v-hi).
__device__ __forceinline__ void split4(f32x4 v, u32x2& hi, u32x2& lo) {
  unsigned h0 = cvt_pk_bf16(v[0], v[1]);
  unsigned h1 = cvt_pk_bf16(v[2], v[3]);
  float f0 = __uint_as_float(h0 << 16);
  float f1 = __uint_as_float(h0 & 0xFFFF0000u);
  float f2 = __uint_as_float(h1 << 16);
  float f3 = __uint_as_float(h1 & 0xFFFF0000u);
  lo[0] = cvt_pk_bf16(v[0] - f0, v[1] - f1);
  lo[1] = cvt_pk_bf16(v[2] - f2, v[3] - f3);
  hi[0] = h0; hi[1] = h1;
}

__device__ __forceinline__ float fast_tanh(float x) {
  // tanh(x) = 1 - 2/(exp(2x)+1); saturates correctly at +-inf, NaN-free for finite x.
  float e = __expf(2.0f * x);
  return 1.0f - 2.0f * __builtin_amdgcn_rcpf(e + 1.0f);
}

__global__ __launch_bounds__(512, 4) void gemm_split_tanh(
    const float* __restrict__ X, const float* __restrict__ Wm,
    const float* __restrict__ avec, const float* __restrict__ bvec,
    float* __restrict__ out) {
  // LDS planes: 0=Ahi 1=Alo 2=Bhi 3=Blo, each [128 rows][64 bf16] = 16KB; total 64KB.
  // Swizzle: 16B slot index XOR (row&7) -> measured 0 bank conflicts.
  __shared__ unsigned short lds[4][128 * 64];

  const int bid = blockIdx.x;
  const int nB  = bid & 3;        // N fastest: 4 consecutive blocks share the A panel
  const int mB  = bid >> 2;
  const int tid  = threadIdx.x;
  const int lane = tid & 63;
  const int wid  = tid >> 6;      // 8 waves: 2 (M) x 4 (N); each wave owns 64x32
  const int wm = wid >> 2, wn = wid & 3;

  f32x4 acc[4][2];
#pragma unroll
  for (int i = 0; i < 4; ++i)
#pragma unroll
    for (int j = 0; j < 2; ++j) acc[i][j] = {0.f, 0.f, 0.f, 0.f};

  // Staging map: 512 threads x 4 float4 per matrix per K-step (128x64 fp32).
  const int srow  = tid >> 4;     // 0..31 (then +32*i)
  const int scol4 = tid & 15;     // float4 index within the 64-wide row
  const int kcol  = scol4 * 4;    // bf16 column 0..60
  const int soff0 = ((kcol >> 3)) ; // slot index before XOR
  const float* Xb = X  + (size_t)mB * 128 * Kdim;
  const float* Wb = Wm + (size_t)nB * 128 * Kdim;

  f32x4 rA[4], rB[4];
#pragma unroll
  for (int i = 0; i < 4; ++i) {
    const int row = srow + 32 * i;
    rA[i] = *(const f32x4*)(Xb + (size_t)row * Kdim + kcol);
    rB[i] = *(const f32x4*)(Wb + (size_t)row * Kdim + kcol);
  }

  for (int kt = 0; kt < Kdim / 64; ++kt) {
    // ---- split current regs + stage to LDS ----
#pragma unroll
    for (int i = 0; i < 4; ++i) {
      const int row = srow + 32 * i;
      const int off = row * 64 + (((soff0) ^ (row & 7)) << 3) + (kcol & 7);
      u32x2 h, l;
      split4(rA[i], h, l);
      *(u32x2*)&lds[0][off] = h;
      *(u32x2*)&lds[1][off] = l;
      split4(rB[i], h, l);
      *(u32x2*)&lds[2][off] = h;
      *(u32x2*)&lds[3][off] = l;
    }
    __syncthreads();

    // ---- issue next K-tile loads (latency hides under MFMA below) ----
    if (kt != Kdim / 64 - 1) {
      const int kbase = (kt + 1) * 64;
#pragma unroll
      for (int i = 0; i < 4; ++i) {
        const int row = srow + 32 * i;
        rA[i] = *(const f32x4*)(Xb + (size_t)row * Kdim + kbase + kcol);
        rB[i] = *(const f32x4*)(Wb + (size_t)row * Kdim + kbase + kcol);
      }
    }

    // ---- compute on staged tile ----
#pragma unroll
    for (int ks = 0; ks < 2; ++ks) {
      const int slotBase = ks * 4 + (lane >> 4);
      bf16x8 bh[2], bl[2];
#pragma unroll
      for (int ni = 0; ni < 2; ++ni) {
        const int row = wn * 32 + ni * 16 + (lane & 15);
        const int off = row * 64 + ((slotBase ^ (row & 7)) << 3);
        bh[ni] = *(const bf16x8*)&lds[2][off];
        bl[ni] = *(const bf16x8*)&lds[3][off];
      }
#pragma unroll
      for (int mi = 0; mi < 4; ++mi) {
        const int row = wm * 64 + mi * 16 + (lane & 15);
        const int off = row * 64 + ((slotBase ^ (row & 7)) << 3);
        bf16x8 ah = *(const bf16x8*)&lds[0][off];
        bf16x8 al = *(const bf16x8*)&lds[1][off];
#pragma unroll
        for (int ni = 0; ni < 2; ++ni) {
          acc[mi][ni] = __builtin_amdgcn_mfma_f32_16x16x32_bf16(ah, bh[ni], acc[mi][ni], 0, 0, 0);
          acc[mi][ni] = __builtin_amdgcn_mfma_f32_16x16x32_bf16(ah, bl[ni], acc[mi][ni], 0, 0, 0);
          acc[mi][ni] = __builtin_amdgcn_mfma_f32_16x16x32_bf16(al, bh[ni], acc[mi][ni], 0, 0, 0);
        }
      }
    }
    __syncthreads();
  }

  // Epilogue: C/D layout for 16x16x32: col = lane&15, row = (lane>>4)*4 + reg.
  const int c  = lane & 15;
  const int rq = (lane >> 4) * 4;
#pragma unroll
  for (int ni = 0; ni < 2; ++ni) {
    const int gc = nB * 128 + wn * 32 + ni * 16 + c;
    const float aa = avec[gc];
    const float bb = bvec[gc];
#pragma unroll
    for (int mi = 0; mi < 4; ++mi) {
      const int gr = mB * 128 + wm * 64 + mi * 16 + rq;
      f32x4 v = acc[mi][ni];
#pragma unroll
      for (int j = 0; j < 4; ++j) {
        out[(size_t)(gr + j) * Ndim + gc] = fast_tanh(aa * v[j] + bb);
      }
    }
  }
}

extern "C" void kernel_launch(void* const* d_in, const int* in_sizes, int n_in,
                              void* d_out, int out_size, void* d_ws, size_t ws_size,
                              hipStream_t stream) {
  const float* X  = (const float*)d_in[0];
  const float* Wm = (const float*)d_in[1];
  const float* av = (const float*)d_in[2];
  const float* bv = (const float*)d_in[3];
  float* out = (float*)d_out;
  dim3 grid((Mdim / 128) * (Ndim / 128));  // 1024 blocks, N fastest within the index
  dim3 block(512);
  gemm_split_tanh<<<grid, block, 0, stream>>>(X, Wm, av, bv, out);
}